// Round 15
// baseline (1809.408 us; speedup 1.0000x reference)
//
#include <hip/hip_runtime.h>

#define NGRAPH 4
#define N0 20000
#define EDG 320000
#define KP1 12000
#define KP2 7200
#define KP3 3600

typedef unsigned short u16;
typedef unsigned int u32;
typedef unsigned long long u64;
typedef short s16x8 __attribute__((ext_vector_type(8)));   // 8 bf16 lanes for MFMA
typedef u16 u16x4 __attribute__((ext_vector_type(4)));
typedef u16 u16x8 __attribute__((ext_vector_type(8)));
typedef float f32x4 __attribute__((ext_vector_type(4)));

__device__ __forceinline__ float b2f(u16 v){ return __uint_as_float(((u32)v)<<16); }
__device__ __forceinline__ u16 f2bf(float f){
  u32 u=__float_as_uint(f); u32 r=(u + 0x7FFFu + ((u>>16)&1u))>>16; return (u16)r;
}

// ---- probe/debug ----
__global__ void k_probe(float* dout, int n, float code){
  int i = blockIdx.x*256 + threadIdx.x;
  if (i >= n) return;
  dout[i] = (i == 0) ? code : 12345.0f;
}

__global__ void k_zero_i32(int* p, int n){
  int i = blockIdx.x*256 + threadIdx.x;
  if (i < n) p[i] = 0;
}

// W[K][N] fp32 -> Wt_hi/Wt_lo[N][K] bf16 (transpose + Dekker split)
__global__ void k_castw2(const float* W, u16* Wth, u16* Wtl, int K, int N){
  __shared__ float tile[32][33];
  int k0 = blockIdx.x*32, n0 = blockIdx.y*32;
  int tx = threadIdx.x & 31, ty = threadIdx.x >> 5;
  for (int r = ty; r < 32; r += 8)
    tile[r][tx] = W[(long)(k0+r)*N + n0 + tx];
  __syncthreads();
  for (int r = ty; r < 32; r += 8){
    float v = tile[tx][r];
    u16 hi = f2bf(v);
    float rs = v - b2f(hi);
    Wth[(long)(n0+r)*K + k0 + tx] = hi;
    Wtl[(long)(n0+r)*K + k0 + tx] = f2bf(rs);
  }
}

// ---- stage-0 graph build ----
__global__ void k_edges_init(const int* ei, int* esrc, int* edst){
  int idx = blockIdx.x*256 + threadIdx.x;
  if (idx >= NGRAPH*EDG) return;
  int g = idx / EDG, e = idx - g*EDG;
  esrc[idx] = ei[(g*2+0)*EDG + e];
  edst[idx] = ei[(g*2+1)*EDG + e];
}

__global__ void k_deg(const int* esrc, const int* edst, int* deg, int n){
  int idx = blockIdx.x*256 + threadIdx.x;
  if (idx >= NGRAPH*EDG) return;
  atomicAdd(&deg[(idx/EDG)*n + edst[idx]], 1);
}

// ---- hierarchical exclusive scan (dinv folded into pass 1; cursor folded into pass 3) ----
__global__ __launch_bounds__(1024) void k_scan1(const int* deg, int* offs, int* bsum,
                                                float* dinv, int n){
  int tid = threadIdx.x;
  int i = blockIdx.x*1024 + tid;
  __shared__ int buf[1024];
  int v = (i < n) ? deg[i] : 0;
  if (i < n) dinv[i] = (v > 0) ? rsqrtf((float)v) : 0.0f;
  buf[tid] = v;
  __syncthreads();
  for (int off = 1; off < 1024; off <<= 1){
    int xv = (tid >= off) ? buf[tid-off] : 0;
    __syncthreads();
    buf[tid] += xv;
    __syncthreads();
  }
  if (i < n) offs[i] = buf[tid] - v;
  if (tid == 1023) bsum[blockIdx.x] = buf[1023];
}

__global__ __launch_bounds__(128) void k_scan2(int* bsum, int* offs, int nb, int n){
  int t = threadIdx.x;
  int v = (t < nb) ? bsum[t] : 0;
  __shared__ int buf[128];
  buf[t] = v;
  __syncthreads();
  for (int off = 1; off < 128; off <<= 1){
    int x = (t >= off) ? buf[t-off] : 0;
    __syncthreads();
    buf[t] += x;
    __syncthreads();
  }
  if (t < nb) bsum[t] = buf[t] - v;
  if (t == 127) offs[n] = buf[127];
}

__global__ __launch_bounds__(1024) void k_scan3(int* offs, const int* bsum, int* cursor, int n){
  int i = blockIdx.x*1024 + threadIdx.x;
  if (i < n){
    int v = offs[i] + bsum[blockIdx.x];
    offs[i] = v;
    cursor[i] = v;
  }
}

__global__ void k_csrfill(const int* esrc, const int* edst, const float* dinv,
                          int* cursor, int* csr_src, float* csr_norm, int n){
  int idx = blockIdx.x*256 + threadIdx.x;
  if (idx >= NGRAPH*EDG) return;
  int g = idx/EDG;
  int gs = g*n + esrc[idx], gd = g*n + edst[idx];
  int pos = atomicAdd(&cursor[gd], 1);
  csr_src[pos] = gs;
  csr_norm[pos] = dinv[gs]*dinv[gd];
}

// ---- CSR compaction for stages 1-3 ----
__global__ void k_filterdeg(const int* perm, const int* mapping,
                            const int* offs_o, const int* deg_o, const int* csrs_o,
                            int* deg_n, int n_old, int k, int mtot){
  int m = blockIdx.x*256 + threadIdx.x;
  if (m >= mtot) return;
  int g = m / k;
  int gio = g*n_old + perm[m];
  int p0 = offs_o[gio], p1 = p0 + deg_o[gio];
  int c = 0;
  for (int p = p0; p < p1; ++p)
    if (mapping[csrs_o[p]] >= 0) ++c;
  deg_n[m] = c;
}

__global__ void k_filterfill(const int* perm, const int* mapping,
                             const int* offs_o, const int* deg_o, const int* csrs_o,
                             const int* offs_n, const float* dinv_n,
                             int* csrs_n, float* csrn_n, int n_old, int k, int mtot){
  int m = blockIdx.x*256 + threadIdx.x;
  if (m >= mtot) return;
  int g = m / k;
  int gio = g*n_old + perm[m];
  int p0 = offs_o[gio], p1 = p0 + deg_o[gio];
  int pos = offs_n[m];
  float dd = dinv_n[m];
  for (int p = p0; p < p1; ++p){
    int sm = mapping[csrs_o[p]];
    if (sm >= 0){
      int sg = g*k + sm;
      csrs_n[pos] = sg;
      csrn_n[pos] = dinv_n[sg]*dd;
      ++pos;
    }
  }
}

// ---- split-bf16 MFMA GEMM, 128x128 tile: H[M][Nc](fp32) = A[M][K](fp32) @ Wt[Nc][K]^T ----
__global__ __launch_bounds__(256) void k_gemm3(const float* A, const u16* Bh_, const u16* Bl_,
                                               float* C, int K, int Nc){
  __shared__ u16 Ah[128][40];
  __shared__ u16 Al[128][40];
  __shared__ u16 Bh[128][40];
  __shared__ u16 Bl[128][40];
  const int n0 = blockIdx.x*128, m0 = blockIdx.y*128;
  const int tid = threadIdx.x, w = tid>>6, lane = tid&63;
  const int wr = w>>1, wc = w&1;
  const int fr = lane&15, fq = lane>>4;
  const int ar = tid>>3, ac = (tid&7)*4;
  const int br = tid>>2, bc = (tid&3)*8;
  f32x4 acc[4][4];
  #pragma unroll
  for (int i=0;i<4;++i)
    #pragma unroll
    for (int j=0;j<4;++j){ acc[i][j][0]=0.f; acc[i][j][1]=0.f; acc[i][j][2]=0.f; acc[i][j][3]=0.f; }
  for (int k0 = 0; k0 < K; k0 += 32){
    __syncthreads();
    #pragma unroll
    for (int i = 0; i < 4; ++i){
      int row = ar + i*32;
      float4 av = *(const float4*)(A + (long)(m0+row)*K + k0 + ac);
      float vs[4] = {av.x, av.y, av.z, av.w};
      u16x4 h, l;
      #pragma unroll
      for (int j = 0; j < 4; ++j){
        u16 hi = f2bf(vs[j]);
        h[j] = hi;
        l[j] = f2bf(vs[j] - b2f(hi));
      }
      *(u16x4*)&Ah[row][ac] = h;
      *(u16x4*)&Al[row][ac] = l;
    }
    #pragma unroll
    for (int i = 0; i < 2; ++i){
      int row = br + i*64;
      *(u16x8*)&Bh[row][bc] = *(const u16x8*)(Bh_ + (long)(n0+row)*K + k0 + bc);
      *(u16x8*)&Bl[row][bc] = *(const u16x8*)(Bl_ + (long)(n0+row)*K + k0 + bc);
    }
    __syncthreads();
    s16x8 fah[4], fal[4], fbh[4], fbl[4];
    #pragma unroll
    for (int fm = 0; fm < 4; ++fm){
      fah[fm] = *(const s16x8*)&Ah[wr*64 + fm*16 + fr][fq*8];
      fal[fm] = *(const s16x8*)&Al[wr*64 + fm*16 + fr][fq*8];
    }
    #pragma unroll
    for (int fn = 0; fn < 4; ++fn){
      fbh[fn] = *(const s16x8*)&Bh[wc*64 + fn*16 + fr][fq*8];
      fbl[fn] = *(const s16x8*)&Bl[wc*64 + fn*16 + fr][fq*8];
    }
    #pragma unroll
    for (int fm = 0; fm < 4; ++fm)
      #pragma unroll
      for (int fn = 0; fn < 4; ++fn){
        acc[fm][fn] = __builtin_amdgcn_mfma_f32_16x16x32_bf16(fal[fm], fbh[fn], acc[fm][fn], 0, 0, 0);
        acc[fm][fn] = __builtin_amdgcn_mfma_f32_16x16x32_bf16(fah[fm], fbl[fn], acc[fm][fn], 0, 0, 0);
        acc[fm][fn] = __builtin_amdgcn_mfma_f32_16x16x32_bf16(fah[fm], fbh[fn], acc[fm][fn], 0, 0, 0);
      }
  }
  #pragma unroll
  for (int fm = 0; fm < 4; ++fm){
    const int r0 = m0 + wr*64 + fm*16 + fq*4;
    #pragma unroll
    for (int fn = 0; fn < 4; ++fn){
      const int c0 = n0 + wc*64 + fn*16 + fr;
      #pragma unroll
      for (int r = 0; r < 4; ++r)
        C[(long)(r0+r)*Nc + c0] = acc[fm][fn][r];
    }
  }
}

// ---- aggregation: edge loop unrolled x2 for memory-level parallelism.
// Accumulation order preserved (e0 then e1) -> bit-identical to serial version.
template<int D>
__global__ void k_agg(const float* hW, const int* offs, const int* deg,
                      const int* csr_src, const float* csr_norm,
                      const float* bias, float* out, int ntot){
  int node = blockIdx.x*4 + (threadIdx.x>>6);
  if (node >= ntot) return;
  int lane = threadIdx.x & 63;
  const int V = D/256;
  f32x4 acc[V];
  #pragma unroll
  for (int j=0;j<V;++j){ acc[j][0]=0.f; acc[j][1]=0.f; acc[j][2]=0.f; acc[j][3]=0.f; }
  int p0 = offs[node], p1 = p0 + deg[node];
  int p = p0;
  for (; p + 1 < p1; p += 2){
    int s0 = csr_src[p],   s1 = csr_src[p+1];
    float n0 = csr_norm[p], n1 = csr_norm[p+1];
    const float* r0 = hW + (long)s0*D + lane*4;
    const float* r1 = hW + (long)s1*D + lane*4;
    f32x4 v0[V], v1[V];
    #pragma unroll
    for (int j=0;j<V;++j) v0[j] = *(const f32x4*)(r0 + j*256);
    #pragma unroll
    for (int j=0;j<V;++j) v1[j] = *(const f32x4*)(r1 + j*256);
    #pragma unroll
    for (int j=0;j<V;++j){ acc[j] += n0*v0[j]; acc[j] += n1*v1[j]; }
  }
  if (p < p1){
    int s0 = csr_src[p];
    float n0 = csr_norm[p];
    const float* r0 = hW + (long)s0*D + lane*4;
    #pragma unroll
    for (int j=0;j<V;++j) acc[j] += n0 * (*(const f32x4*)(r0 + j*256));
  }
  float* orow = out + (long)node*D + lane*4;
  const float* brow = bias + lane*4;
  #pragma unroll
  for (int j=0;j<V;++j){
    f32x4 b = *(const f32x4*)(brow + j*256);
    *(f32x4*)(orow + j*256) = acc[j] + b;
  }
}

// ---- batchnorm stats ----
template<int D>
__global__ void k_bnpart(const float* h, float* part, int n, int NB){
  int g = blockIdx.y, bx = blockIdx.x;
  int r0 = bx*256;
  int rows = n - r0; if (rows > 256) rows = 256;
  const int CPT = D/256;
  float s[CPT], q[CPT];
  #pragma unroll
  for (int j=0;j<CPT;++j){ s[j]=0.0f; q[j]=0.0f; }
  const float* base = h + ((long)g*n + r0)*D;
  for (int r = 0; r < rows; ++r)
    #pragma unroll
    for (int j=0;j<CPT;++j){
      float v = base[(long)r*D + threadIdx.x + j*256];
      s[j] += v; q[j] += v*v;
    }
  float* o = part + ((long)(g*NB + bx)*2)*D;
  #pragma unroll
  for (int j=0;j<CPT;++j){
    o[threadIdx.x + j*256]     = s[j];
    o[D + threadIdx.x + j*256] = q[j];
  }
}

__global__ void k_bnfin(const float* part, float* mean, float* rstd, int n, int D, int NB){
  int idx = blockIdx.x*256 + threadIdx.x;
  if (idx >= NGRAPH*D) return;
  int g = idx / D, c = idx - g*D;
  float s = 0.0f, q = 0.0f;
  for (int b = 0; b < NB; ++b){
    const float* o = part + ((long)(g*NB + b)*2)*D;
    s += o[c]; q += o[D + c];
  }
  float m = s/(float)n;
  float v = q/(float)n - m*m;
  mean[idx] = m;
  rstd[idx] = rsqrtf(v + 1e-5f);
}

// ---- fused BN+ReLU+score-dots ----
template<int D>
__global__ void k_bnrelu_dots(float* h, const float* mean, const float* rstd,
                              const float* gam, const float* bet,
                              const float* wrel, const float* wroot,
                              float* r, float* t, int n, int ntot){
  int node = blockIdx.x*4 + (threadIdx.x>>6);
  if (node >= ntot) return;
  int lane = threadIdx.x & 63;
  int g = node / n;
  const float* mu = mean + g*D;
  const float* rs = rstd + g*D;
  float* row = h + (long)node*D;
  float sr = 0.0f, st = 0.0f;
  #pragma unroll
  for (int j = 0; j < D/64; ++j){
    int c = lane + j*64;
    float v = (row[c] - mu[c])*rs[c]*gam[c] + bet[c];
    v = fmaxf(v, 0.0f);
    row[c] = v;
    sr += v*wrel[c];
    st += v*wroot[c];
  }
  for (int o = 32; o > 0; o >>= 1){
    sr += __shfl_down(sr, o);
    st += __shfl_down(st, o);
  }
  if (lane == 0){ r[node] = sr; t[node] = st; }
}

// ---- score + key generation fused ----
__global__ void k_score(const float* r, const float* t, const int* offs, const int* deg,
                        const int* csr_src, const float* brel, float* score,
                        u64* keys, int n, int ntot){
  int i = blockIdx.x*256 + threadIdx.x;
  if (i >= ntot) return;
  float a = 0.0f;
  int p0 = offs[i], p1 = p0 + deg[i];
  for (int p = p0; p < p1; ++p) a += r[csr_src[p]];
  float sc = tanhf(a + brel[0] + t[i]);
  score[i] = sc;
  u32 u = __float_as_uint(sc);
  u = (u & 0x80000000u) ? ~u : (u | 0x80000000u);
  keys[i] = ((u64)u << 32) | (u64)(0xFFFFFFFFu - (u32)(i % n));
}

// ---- exact top-k radix select (zeroes cnt[g] for the following k_select) ----
__global__ __launch_bounds__(1024) void k_radix(const u64* keys, u64* Tout, int* cnt, int n, int k){
  int g = blockIdx.x;
  const u64* kk = keys + (long)g*n;
  __shared__ u32 h0[2048];
  __shared__ u32 h1[2048];
  __shared__ u64 s_prefix;
  __shared__ int s_remaining;
  __shared__ int s_bin;
  if (threadIdx.x == 0){ s_prefix = 0ull; s_remaining = k; cnt[g] = 0; }
  int consumed = 0;
  for (int round = 0; round < 6; ++round){
    int nb = (round < 5) ? 11 : 9;
    int shift = 64 - consumed - nb;
    int bins = 1 << nb;
    for (int i = threadIdx.x; i < bins; i += 1024) h0[i] = 0u;
    __syncthreads();
    u64 pref = s_prefix;
    int rem = s_remaining;
    for (int i = threadIdx.x; i < n; i += 1024){
      u64 key = kk[i];
      if (consumed == 0 || (key >> (64 - consumed)) == pref)
        atomicAdd(&h0[(u32)((key >> shift) & (u64)(bins-1))], 1u);
    }
    __syncthreads();
    u32* src = h0; u32* dst = h1;
    for (int off = 1; off < bins; off <<= 1){
      for (int i = threadIdx.x; i < bins; i += 1024)
        dst[i] = src[i] + ((i + off < bins) ? src[i + off] : 0u);
      __syncthreads();
      u32* tmp = src; src = dst; dst = tmp;
    }
    for (int i = threadIdx.x; i < bins; i += 1024){
      int Sb  = (int)src[i];
      int Sb1 = (i + 1 < bins) ? (int)src[i+1] : 0;
      if (Sb >= rem && (i == bins-1 || Sb1 < rem)){
        s_bin = i;
        s_remaining = rem - Sb1;
      }
    }
    __syncthreads();
    if (threadIdx.x == 0) s_prefix = (s_prefix << nb) | (u64)s_bin;
    consumed += nb;
    __syncthreads();
  }
  if (threadIdx.x == 0) Tout[g] = s_prefix;
}

// ---- wave-aggregated select ----
__global__ void k_select(const u64* keys, const u64* T, int* mapping,
                         int* perm, int* cnt, int n, int k, int ntot){
  int gi = blockIdx.x*256 + threadIdx.x;
  int lane = threadIdx.x & 63;
  if (gi - lane >= ntot) return;
  int g = gi / n;
  bool sel = keys[gi] >= T[g];
  u64 ball = __ballot(sel);
  u64 lt = (1ull << lane) - 1ull;
  int g0 = __shfl(g, 0);
  u64 sameg = __ballot(g == g0);
  int id = -1;
  if (g == g0){
    u64 mA = ball & sameg;
    int baseA = 0;
    if (lane == 0 && mA) baseA = atomicAdd(&cnt[g0], __popcll(mA));
    baseA = __shfl(baseA, 0);
    if (sel) id = baseA + __popcll(mA & lt);
  } else {
    u64 blanes = ~sameg;
    int firstB = (int)(__ffsll((long long)blanes) - 1);
    u64 mB = ball & blanes;
    int baseB = 0;
    if (lane == firstB && mB) baseB = atomicAdd(&cnt[g], __popcll(mB));
    baseB = __shfl(baseB, firstB);
    if (sel) id = baseB + __popcll(mB & lt);
  }
  mapping[gi] = id;
  if (id >= 0) perm[g*k + id] = gi - g*n;
}

__global__ void k_poolcopy(const float* h, const float* score, const int* perm,
                           float* outA, int n, int k, int D, int mtot){
  int m = blockIdx.x*4 + (threadIdx.x>>6);
  if (m >= mtot) return;
  int lane = threadIdx.x & 63;
  int g = m / k;
  int gi = g*n + perm[m];
  float sc = score[gi];
  const float* row = h + (long)gi*D;
  float* orow = outA + (long)m*D;
  for (int c = lane; c < D; c += 64) orow[c] = row[c]*sc;
}

// ---- tail: partial max + fused finish ----
__global__ void k_maxpart(const float* h, float* part){
  int g = blockIdx.y, b = blockIdx.x, c = threadIdx.x;
  int r0 = b*240;
  const float* base = h + ((long)g*KP3 + r0)*256;
  float m = -3.4e38f;
  for (int r = 0; r < 240; ++r) m = fmaxf(m, base[(long)r*256 + c]);
  part[(g*15 + b)*256 + c] = m;
}

__global__ void k_final(const float* part, const float* lw, const float* lb,
                        const float* l2w, const float* l2b, float* dout){
  __shared__ float sx[256];
  __shared__ float sp[256];
  int c = threadIdx.x;
  float acc4 = 0.0f;
  for (int g = 0; g < NGRAPH; ++g){
    float m = -3.4e38f;
    for (int b = 0; b < 15; ++b) m = fmaxf(m, part[(g*15 + b)*256 + c]);
    acc4 += m;
  }
  float x1 = 0.25f*acc4;
  sx[c] = x1;
  __syncthreads();
  float acc = lb[c];
  for (int j = 0; j < 256; ++j) acc += sx[j]*lw[j*256 + c];
  acc = fmaxf(acc, 0.0f);
  sp[c] = acc*l2w[c];
  __syncthreads();
  for (int off = 128; off > 0; off >>= 1){
    if (c < off) sp[c] += sp[c+off];
    __syncthreads();
  }
  if (c == 0) dout[0] = sp[0] + l2b[0];
  dout[1+c] = sx[c];
}

extern "C" void kernel_launch(void* const* d_in, const int* in_sizes, int n_in,
                              void* d_out, int out_size, void* d_ws, size_t ws_size,
                              hipStream_t stream){
  const float* x  = (const float*)d_in[0];
  const int*   ei = (const int*)d_in[1];
  const float *W1 = (const float*)d_in[2],  *b1 = (const float*)d_in[3];
  const float *W2 = (const float*)d_in[4],  *b2 = (const float*)d_in[5];
  const float *W3 = (const float*)d_in[6],  *b3 = (const float*)d_in[7];
  const float *W4 = (const float*)d_in[8],  *b4 = (const float*)d_in[9];
  const float *g1 = (const float*)d_in[10], *be1 = (const float*)d_in[11];
  const float *g2 = (const float*)d_in[12], *be2 = (const float*)d_in[13];
  const float *g3 = (const float*)d_in[14], *be3 = (const float*)d_in[15];
  const float *p1r = (const float*)d_in[16], *p1b = (const float*)d_in[17], *p1o = (const float*)d_in[18];
  const float *p2r = (const float*)d_in[19], *p2b = (const float*)d_in[20], *p2o = (const float*)d_in[21];
  const float *p3r = (const float*)d_in[22], *p3b = (const float*)d_in[23], *p3o = (const float*)d_in[24];
  const float *lw = (const float*)d_in[25], *lb = (const float*)d_in[26];
  const float *l2w = (const float*)d_in[27], *l2b = (const float*)d_in[28];
  float* dout = (float*)d_out;

  bool ok = (n_in == 29) && (out_size == 257)
         && (in_sizes[0] == NGRAPH*N0*512) && (in_sizes[1] == NGRAPH*2*EDG);
  if (!ok){
    k_probe<<<2,256,0,stream>>>(dout, out_size, 7777777.0f);
    return;
  }

  char* wbase = (char*)d_ws;
  size_t woff = 0;
  auto alloc = [&](size_t bytes) -> void* {
    void* p = wbase + woff;
    woff = (woff + bytes + 255) & ~(size_t)255;
    return p;
  };
  size_t NE = (size_t)NGRAPH*N0;
  size_t RSZ = NE*512*4;
  float* R0 = (float*)alloc(RSZ);
  float* R1 = (float*)alloc(RSZ);
  u16* Wt1h = (u16*)alloc((size_t)512*512*2); u16* Wt1l = (u16*)alloc((size_t)512*512*2);
  u16* Wt2h = (u16*)alloc((size_t)512*512*2); u16* Wt2l = (u16*)alloc((size_t)512*512*2);
  u16* Wt3h = (u16*)alloc((size_t)256*512*2); u16* Wt3l = (u16*)alloc((size_t)256*512*2);
  u16* Wt4h = (u16*)alloc((size_t)256*256*2); u16* Wt4l = (u16*)alloc((size_t)256*256*2);
  int*   esrc  = (int*)alloc((size_t)NGRAPH*EDG*4);
  int*   edst  = (int*)alloc((size_t)NGRAPH*EDG*4);
  int*   csrsA = (int*)  alloc((size_t)NGRAPH*EDG*4);
  float* csrnA = (float*)alloc((size_t)NGRAPH*EDG*4);
  int*   csrsB = (int*)  alloc((size_t)NGRAPH*EDG*4);
  float* csrnB = (float*)alloc((size_t)NGRAPH*EDG*4);
  int*   degA  = (int*)  alloc(NE*4);
  int*   degB  = (int*)  alloc(NE*4);
  int*   offsA = (int*)  alloc((NE+1)*4);
  int*   offsB = (int*)  alloc((NE+1)*4);
  float* dinv  = (float*)alloc(NE*4);
  int*   cursor= (int*)  alloc(NE*4);
  int*   bsum  = (int*)  alloc(128*4);
  float* rbuf  = (float*)alloc(NE*4);
  float* tbuf  = (float*)alloc(NE*4);
  float* sbuf  = (float*)alloc(NE*4);
  u64*   keys  = (u64*)  alloc(NE*8);
  u64*   Tsel  = (u64*)  alloc(NGRAPH*8);
  int*   cnt   = (int*)  alloc(NGRAPH*4);
  int*   mapping = (int*)alloc(NE*4);
  int*   perm  = (int*)  alloc((size_t)NGRAPH*KP1*4);
  float* bnpart= (float*)alloc((size_t)NGRAPH*79*2*512*4);
  float* bnmean= (float*)alloc((size_t)NGRAPH*512*4);
  float* bnrstd= (float*)alloc((size_t)NGRAPH*512*4);
  float* maxpart=(float*)alloc((size_t)NGRAPH*15*256*4);

  if (woff > ws_size){
    k_probe<<<2,256,0,stream>>>(dout, out_size, 8000000.0f + (float)(ws_size >> 20));
    return;
  }

  auto cdiv = [](long a, long b) -> int { return (int)((a + b - 1)/b); };
  long etot = (long)NGRAPH*EDG;

  {
    dim3 g1d(512/32, 512/32);
    k_castw2<<<g1d,256,0,stream>>>(W1, Wt1h, Wt1l, 512, 512);
    k_castw2<<<g1d,256,0,stream>>>(W2, Wt2h, Wt2l, 512, 512);
    dim3 g3d(512/32, 256/32);
    k_castw2<<<g3d,256,0,stream>>>(W3, Wt3h, Wt3l, 512, 256);
    dim3 g4d(256/32, 256/32);
    k_castw2<<<g4d,256,0,stream>>>(W4, Wt4h, Wt4l, 256, 256);
  }
  k_edges_init<<<cdiv(etot,256),256,0,stream>>>(ei, esrc, edst);

  struct SP { int n, din, dout_, knext; const u16 *Wh,*Wl; const float *b,*gam,*bet,*wrel,*brel,*wroot; };
  SP sp[4] = {
    {N0,  512, 512, KP1, Wt1h,Wt1l, b1,g1,be1,p1r,p1b,p1o},
    {KP1, 512, 512, KP2, Wt2h,Wt2l, b2,g2,be2,p2r,p2b,p2o},
    {KP2, 512, 256, KP3, Wt3h,Wt3l, b3,g3,be3,p3r,p3b,p3o},
    {KP3, 256, 256, 0,   Wt4h,Wt4l, b4,0,0,0,0,0},
  };

  float* bufA = R0;
  float* bufB = R1;

  int *deg_c = degA, *offs_c = offsA, *csrs_c = csrsA;
  float *csrn_c = csrnA;
  int *deg_x = degB, *offs_x = offsB, *csrs_x = csrsB;
  float *csrn_x = csrnB;

  for (int s = 0; s < 4; ++s){
    SP& P = sp[s];
    int ntot = NGRAPH*P.n;
    int D = P.dout_;
    const float* Ain = (s == 0) ? x : bufA;
    float* H = bufB;
    float* C = bufA;
    int nb = cdiv(ntot, 1024);

    if (s == 0){
      k_zero_i32<<<cdiv(ntot,256),256,0,stream>>>(deg_c, ntot);
      k_deg<<<cdiv(etot,256),256,0,stream>>>(esrc, edst, deg_c, P.n);
      k_scan1<<<nb,1024,0,stream>>>(deg_c, offs_c, bsum, dinv, ntot);
      k_scan2<<<1,128,0,stream>>>(bsum, offs_c, nb, ntot);
      k_scan3<<<nb,1024,0,stream>>>(offs_c, bsum, cursor, ntot);
      k_csrfill<<<cdiv(etot,256),256,0,stream>>>(esrc, edst, dinv, cursor, csrs_c, csrn_c, P.n);
    } else {
      int n_old = sp[s-1].n;
      k_filterdeg<<<cdiv(ntot,256),256,0,stream>>>(perm, mapping, offs_c, deg_c, csrs_c,
                                                   deg_x, n_old, P.n, ntot);
      k_scan1<<<nb,1024,0,stream>>>(deg_x, offs_x, bsum, dinv, ntot);
      k_scan2<<<1,128,0,stream>>>(bsum, offs_x, nb, ntot);
      k_scan3<<<nb,1024,0,stream>>>(offs_x, bsum, cursor, ntot);
      k_filterfill<<<cdiv(ntot,256),256,0,stream>>>(perm, mapping, offs_c, deg_c, csrs_c,
                                                    offs_x, dinv, csrs_x, csrn_x, n_old, P.n, ntot);
      int* ti; float* tf;
      ti = deg_c;  deg_c  = deg_x;  deg_x  = ti;
      ti = offs_c; offs_c = offs_x; offs_x = ti;
      ti = csrs_c; csrs_c = csrs_x; csrs_x = ti;
      tf = csrn_c; csrn_c = csrn_x; csrn_x = tf;
    }

    {
      dim3 gg(D/128, cdiv(ntot,128));
      k_gemm3<<<gg,256,0,stream>>>(Ain, P.Wh, P.Wl, H, P.din, D);
    }
    if (D == 512)
      hipLaunchKernelGGL(HIP_KERNEL_NAME(k_agg<512>), dim3(ntot/4), dim3(256), 0, stream,
                         H, offs_c, deg_c, csrs_c, csrn_c, P.b, C, ntot);
    else
      hipLaunchKernelGGL(HIP_KERNEL_NAME(k_agg<256>), dim3(ntot/4), dim3(256), 0, stream,
                         H, offs_c, deg_c, csrs_c, csrn_c, P.b, C, ntot);
    if (s < 3){
      int NB = cdiv(P.n, 256);
      if (D == 512)
        hipLaunchKernelGGL(HIP_KERNEL_NAME(k_bnpart<512>), dim3(NB,NGRAPH), dim3(256), 0, stream,
                           C, bnpart, P.n, NB);
      else
        hipLaunchKernelGGL(HIP_KERNEL_NAME(k_bnpart<256>), dim3(NB,NGRAPH), dim3(256), 0, stream,
                           C, bnpart, P.n, NB);
      k_bnfin<<<cdiv((long)NGRAPH*D,256),256,0,stream>>>(bnpart, bnmean, bnrstd, P.n, D, NB);
      if (D == 512)
        hipLaunchKernelGGL(HIP_KERNEL_NAME(k_bnrelu_dots<512>), dim3(ntot/4), dim3(256), 0, stream,
                           C, bnmean, bnrstd, P.gam, P.bet, P.wrel, P.wroot, rbuf, tbuf, P.n, ntot);
      else
        hipLaunchKernelGGL(HIP_KERNEL_NAME(k_bnrelu_dots<256>), dim3(ntot/4), dim3(256), 0, stream,
                           C, bnmean, bnrstd, P.gam, P.bet, P.wrel, P.wroot, rbuf, tbuf, P.n, ntot);
      k_score<<<cdiv(ntot,256),256,0,stream>>>(rbuf, tbuf, offs_c, deg_c, csrs_c, P.brel,
                                               sbuf, keys, P.n, ntot);
      k_radix<<<NGRAPH,1024,0,stream>>>(keys, Tsel, cnt, P.n, P.knext);
      k_select<<<cdiv(ntot,256),256,0,stream>>>(keys, Tsel, mapping, perm, cnt, P.n, P.knext, ntot);
      int mtot = NGRAPH*P.knext;
      k_poolcopy<<<mtot/4,256,0,stream>>>(C, sbuf, perm, bufB, P.n, P.knext, D, mtot);
      float* tmp = bufA; bufA = bufB; bufB = tmp;
    } else {
      k_maxpart<<<dim3(15,NGRAPH),256,0,stream>>>(C, maxpart);
      k_final<<<1,256,0,stream>>>(maxpart, lw, lb, l2w, l2b, dout);
    }
  }
}

// Round 16
// 1798.141 us; speedup vs baseline: 1.0063x; 1.0063x over previous
//
#include <hip/hip_runtime.h>

#define NGRAPH 4
#define N0 20000
#define EDG 320000
#define KP1 12000
#define KP2 7200
#define KP3 3600

typedef unsigned short u16;
typedef unsigned int u32;
typedef unsigned long long u64;
typedef short s16x8 __attribute__((ext_vector_type(8)));   // 8 bf16 lanes for MFMA
typedef u16 u16x4 __attribute__((ext_vector_type(4)));
typedef u16 u16x8 __attribute__((ext_vector_type(8)));
typedef float f32x4 __attribute__((ext_vector_type(4)));

__device__ __forceinline__ float b2f(u16 v){ return __uint_as_float(((u32)v)<<16); }
__device__ __forceinline__ u16 f2bf(float f){
  u32 u=__float_as_uint(f); u32 r=(u + 0x7FFFu + ((u>>16)&1u))>>16; return (u16)r;
}

// ---- probe/debug ----
__global__ void k_probe(float* dout, int n, float code){
  int i = blockIdx.x*256 + threadIdx.x;
  if (i >= n) return;
  dout[i] = (i == 0) ? code : 12345.0f;
}

__global__ void k_zero_i32(int* p, int n){
  int i = blockIdx.x*256 + threadIdx.x;
  if (i < n) p[i] = 0;
}

// W[K][N] fp32 -> Wt_hi/Wt_lo[N][K] bf16 (transpose + Dekker split)
__global__ void k_castw2(const float* W, u16* Wth, u16* Wtl, int K, int N){
  __shared__ float tile[32][33];
  int k0 = blockIdx.x*32, n0 = blockIdx.y*32;
  int tx = threadIdx.x & 31, ty = threadIdx.x >> 5;
  for (int r = ty; r < 32; r += 8)
    tile[r][tx] = W[(long)(k0+r)*N + n0 + tx];
  __syncthreads();
  for (int r = ty; r < 32; r += 8){
    float v = tile[tx][r];
    u16 hi = f2bf(v);
    float rs = v - b2f(hi);
    Wth[(long)(n0+r)*K + k0 + tx] = hi;
    Wtl[(long)(n0+r)*K + k0 + tx] = f2bf(rs);
  }
}

// ---- stage-0 graph build ----
__global__ void k_edges_init(const int* ei, int* esrc, int* edst){
  int idx = blockIdx.x*256 + threadIdx.x;
  if (idx >= NGRAPH*EDG) return;
  int g = idx / EDG, e = idx - g*EDG;
  esrc[idx] = ei[(g*2+0)*EDG + e];
  edst[idx] = ei[(g*2+1)*EDG + e];
}

__global__ void k_deg(const int* esrc, const int* edst, int* deg, int n){
  int idx = blockIdx.x*256 + threadIdx.x;
  if (idx >= NGRAPH*EDG) return;
  atomicAdd(&deg[(idx/EDG)*n + edst[idx]], 1);
}

// ---- hierarchical exclusive scan (dinv folded into pass 1; cursor folded into pass 3) ----
__global__ __launch_bounds__(1024) void k_scan1(const int* deg, int* offs, int* bsum,
                                                float* dinv, int n){
  int tid = threadIdx.x;
  int i = blockIdx.x*1024 + tid;
  __shared__ int buf[1024];
  int v = (i < n) ? deg[i] : 0;
  if (i < n) dinv[i] = (v > 0) ? rsqrtf((float)v) : 0.0f;
  buf[tid] = v;
  __syncthreads();
  for (int off = 1; off < 1024; off <<= 1){
    int xv = (tid >= off) ? buf[tid-off] : 0;
    __syncthreads();
    buf[tid] += xv;
    __syncthreads();
  }
  if (i < n) offs[i] = buf[tid] - v;
  if (tid == 1023) bsum[blockIdx.x] = buf[1023];
}

__global__ __launch_bounds__(128) void k_scan2(int* bsum, int* offs, int nb, int n){
  int t = threadIdx.x;
  int v = (t < nb) ? bsum[t] : 0;
  __shared__ int buf[128];
  buf[t] = v;
  __syncthreads();
  for (int off = 1; off < 128; off <<= 1){
    int x = (t >= off) ? buf[t-off] : 0;
    __syncthreads();
    buf[t] += x;
    __syncthreads();
  }
  if (t < nb) bsum[t] = buf[t] - v;
  if (t == 127) offs[n] = buf[127];
}

__global__ __launch_bounds__(1024) void k_scan3(int* offs, const int* bsum, int* cursor, int n){
  int i = blockIdx.x*1024 + threadIdx.x;
  if (i < n){
    int v = offs[i] + bsum[blockIdx.x];
    offs[i] = v;
    cursor[i] = v;
  }
}

__global__ void k_csrfill(const int* esrc, const int* edst, const float* dinv,
                          int* cursor, int* csr_src, float* csr_norm, int n){
  int idx = blockIdx.x*256 + threadIdx.x;
  if (idx >= NGRAPH*EDG) return;
  int g = idx/EDG;
  int gs = g*n + esrc[idx], gd = g*n + edst[idx];
  int pos = atomicAdd(&cursor[gd], 1);
  csr_src[pos] = gs;
  csr_norm[pos] = dinv[gs]*dinv[gd];
}

// ---- CSR compaction for stages 1-3 ----
__global__ void k_filterdeg(const int* perm, const int* mapping,
                            const int* offs_o, const int* deg_o, const int* csrs_o,
                            int* deg_n, int n_old, int k, int mtot){
  int m = blockIdx.x*256 + threadIdx.x;
  if (m >= mtot) return;
  int g = m / k;
  int gio = g*n_old + perm[m];
  int p0 = offs_o[gio], p1 = p0 + deg_o[gio];
  int c = 0;
  for (int p = p0; p < p1; ++p)
    if (mapping[csrs_o[p]] >= 0) ++c;
  deg_n[m] = c;
}

__global__ void k_filterfill(const int* perm, const int* mapping,
                             const int* offs_o, const int* deg_o, const int* csrs_o,
                             const int* offs_n, const float* dinv_n,
                             int* csrs_n, float* csrn_n, int n_old, int k, int mtot){
  int m = blockIdx.x*256 + threadIdx.x;
  if (m >= mtot) return;
  int g = m / k;
  int gio = g*n_old + perm[m];
  int p0 = offs_o[gio], p1 = p0 + deg_o[gio];
  int pos = offs_n[m];
  float dd = dinv_n[m];
  for (int p = p0; p < p1; ++p){
    int sm = mapping[csrs_o[p]];
    if (sm >= 0){
      int sg = g*k + sm;
      csrs_n[pos] = sg;
      csrn_n[pos] = dinv_n[sg]*dd;
      ++pos;
    }
  }
}

// ---- split-bf16 MFMA GEMM, 128x128 tile: H[M][Nc](fp32) = A[M][K](fp32) @ Wt[Nc][K]^T ----
__global__ __launch_bounds__(256) void k_gemm3(const float* A, const u16* Bh_, const u16* Bl_,
                                               float* C, int K, int Nc){
  __shared__ u16 Ah[128][40];
  __shared__ u16 Al[128][40];
  __shared__ u16 Bh[128][40];
  __shared__ u16 Bl[128][40];
  const int n0 = blockIdx.x*128, m0 = blockIdx.y*128;
  const int tid = threadIdx.x, w = tid>>6, lane = tid&63;
  const int wr = w>>1, wc = w&1;
  const int fr = lane&15, fq = lane>>4;
  const int ar = tid>>3, ac = (tid&7)*4;
  const int br = tid>>2, bc = (tid&3)*8;
  f32x4 acc[4][4];
  #pragma unroll
  for (int i=0;i<4;++i)
    #pragma unroll
    for (int j=0;j<4;++j){ acc[i][j][0]=0.f; acc[i][j][1]=0.f; acc[i][j][2]=0.f; acc[i][j][3]=0.f; }
  for (int k0 = 0; k0 < K; k0 += 32){
    __syncthreads();
    #pragma unroll
    for (int i = 0; i < 4; ++i){
      int row = ar + i*32;
      float4 av = *(const float4*)(A + (long)(m0+row)*K + k0 + ac);
      float vs[4] = {av.x, av.y, av.z, av.w};
      u16x4 h, l;
      #pragma unroll
      for (int j = 0; j < 4; ++j){
        u16 hi = f2bf(vs[j]);
        h[j] = hi;
        l[j] = f2bf(vs[j] - b2f(hi));
      }
      *(u16x4*)&Ah[row][ac] = h;
      *(u16x4*)&Al[row][ac] = l;
    }
    #pragma unroll
    for (int i = 0; i < 2; ++i){
      int row = br + i*64;
      *(u16x8*)&Bh[row][bc] = *(const u16x8*)(Bh_ + (long)(n0+row)*K + k0 + bc);
      *(u16x8*)&Bl[row][bc] = *(const u16x8*)(Bl_ + (long)(n0+row)*K + k0 + bc);
    }
    __syncthreads();
    s16x8 fah[4], fal[4], fbh[4], fbl[4];
    #pragma unroll
    for (int fm = 0; fm < 4; ++fm){
      fah[fm] = *(const s16x8*)&Ah[wr*64 + fm*16 + fr][fq*8];
      fal[fm] = *(const s16x8*)&Al[wr*64 + fm*16 + fr][fq*8];
    }
    #pragma unroll
    for (int fn = 0; fn < 4; ++fn){
      fbh[fn] = *(const s16x8*)&Bh[wc*64 + fn*16 + fr][fq*8];
      fbl[fn] = *(const s16x8*)&Bl[wc*64 + fn*16 + fr][fq*8];
    }
    #pragma unroll
    for (int fm = 0; fm < 4; ++fm)
      #pragma unroll
      for (int fn = 0; fn < 4; ++fn){
        acc[fm][fn] = __builtin_amdgcn_mfma_f32_16x16x32_bf16(fal[fm], fbh[fn], acc[fm][fn], 0, 0, 0);
        acc[fm][fn] = __builtin_amdgcn_mfma_f32_16x16x32_bf16(fah[fm], fbl[fn], acc[fm][fn], 0, 0, 0);
        acc[fm][fn] = __builtin_amdgcn_mfma_f32_16x16x32_bf16(fah[fm], fbh[fn], acc[fm][fn], 0, 0, 0);
      }
  }
  #pragma unroll
  for (int fm = 0; fm < 4; ++fm){
    const int r0 = m0 + wr*64 + fm*16 + fq*4;
    #pragma unroll
    for (int fn = 0; fn < 4; ++fn){
      const int c0 = n0 + wc*64 + fn*16 + fr;
      #pragma unroll
      for (int r = 0; r < 4; ++r)
        C[(long)(r0+r)*Nc + c0] = acc[fm][fn][r];
    }
  }
}

// ---- aggregation ----
template<int D>
__global__ void k_agg(const float* hW, const int* offs, const int* deg,
                      const int* csr_src, const float* csr_norm,
                      const float* bias, float* out, int ntot){
  int node = blockIdx.x*4 + (threadIdx.x>>6);
  if (node >= ntot) return;
  int lane = threadIdx.x & 63;
  const int V = D/256;
  f32x4 acc[V];
  #pragma unroll
  for (int j=0;j<V;++j){ acc[j][0]=0.f; acc[j][1]=0.f; acc[j][2]=0.f; acc[j][3]=0.f; }
  int p0 = offs[node], p1 = p0 + deg[node];
  for (int p = p0; p < p1; ++p) {
    int src = csr_src[p];
    float nm = csr_norm[p];
    const float* row = hW + (long)src*D + lane*4;
    #pragma unroll
    for (int j=0;j<V;++j){
      f32x4 v = *(const f32x4*)(row + j*256);
      acc[j] += nm*v;
    }
  }
  float* orow = out + (long)node*D + lane*4;
  const float* brow = bias + lane*4;
  #pragma unroll
  for (int j=0;j<V;++j){
    f32x4 b = *(const f32x4*)(brow + j*256);
    *(f32x4*)(orow + j*256) = acc[j] + b;
  }
}

// ---- batchnorm stats ----
template<int D>
__global__ void k_bnpart(const float* h, float* part, int n, int NB){
  int g = blockIdx.y, bx = blockIdx.x;
  int r0 = bx*256;
  int rows = n - r0; if (rows > 256) rows = 256;
  const int CPT = D/256;
  float s[CPT], q[CPT];
  #pragma unroll
  for (int j=0;j<CPT;++j){ s[j]=0.0f; q[j]=0.0f; }
  const float* base = h + ((long)g*n + r0)*D;
  for (int r = 0; r < rows; ++r)
    #pragma unroll
    for (int j=0;j<CPT;++j){
      float v = base[(long)r*D + threadIdx.x + j*256];
      s[j] += v; q[j] += v*v;
    }
  float* o = part + ((long)(g*NB + bx)*2)*D;
  #pragma unroll
  for (int j=0;j<CPT;++j){
    o[threadIdx.x + j*256]     = s[j];
    o[D + threadIdx.x + j*256] = q[j];
  }
}

__global__ void k_bnfin(const float* part, float* mean, float* rstd, int n, int D, int NB){
  int idx = blockIdx.x*256 + threadIdx.x;
  if (idx >= NGRAPH*D) return;
  int g = idx / D, c = idx - g*D;
  float s = 0.0f, q = 0.0f;
  for (int b = 0; b < NB; ++b){
    const float* o = part + ((long)(g*NB + b)*2)*D;
    s += o[c]; q += o[D + c];
  }
  float m = s/(float)n;
  float v = q/(float)n - m*m;
  mean[idx] = m;
  rstd[idx] = rsqrtf(v + 1e-5f);
}

// ---- fused BN+ReLU+score-dots ----
template<int D>
__global__ void k_bnrelu_dots(float* h, const float* mean, const float* rstd,
                              const float* gam, const float* bet,
                              const float* wrel, const float* wroot,
                              float* r, float* t, int n, int ntot){
  int node = blockIdx.x*4 + (threadIdx.x>>6);
  if (node >= ntot) return;
  int lane = threadIdx.x & 63;
  int g = node / n;
  const float* mu = mean + g*D;
  const float* rs = rstd + g*D;
  float* row = h + (long)node*D;
  float sr = 0.0f, st = 0.0f;
  #pragma unroll
  for (int j = 0; j < D/64; ++j){
    int c = lane + j*64;
    float v = (row[c] - mu[c])*rs[c]*gam[c] + bet[c];
    v = fmaxf(v, 0.0f);
    row[c] = v;
    sr += v*wrel[c];
    st += v*wroot[c];
  }
  for (int o = 32; o > 0; o >>= 1){
    sr += __shfl_down(sr, o);
    st += __shfl_down(st, o);
  }
  if (lane == 0){ r[node] = sr; t[node] = st; }
}

// ---- score + key generation fused ----
__global__ void k_score(const float* r, const float* t, const int* offs, const int* deg,
                        const int* csr_src, const float* brel, float* score,
                        u64* keys, int n, int ntot){
  int i = blockIdx.x*256 + threadIdx.x;
  if (i >= ntot) return;
  float a = 0.0f;
  int p0 = offs[i], p1 = p0 + deg[i];
  for (int p = p0; p < p1; ++p) a += r[csr_src[p]];
  float sc = tanhf(a + brel[0] + t[i]);
  score[i] = sc;
  u32 u = __float_as_uint(sc);
  u = (u & 0x80000000u) ? ~u : (u | 0x80000000u);
  keys[i] = ((u64)u << 32) | (u64)(0xFFFFFFFFu - (u32)(i % n));
}

// ---- exact top-k radix select (zeroes cnt[g] for the following k_select) ----
__global__ __launch_bounds__(1024) void k_radix(const u64* keys, u64* Tout, int* cnt, int n, int k){
  int g = blockIdx.x;
  const u64* kk = keys + (long)g*n;
  __shared__ u32 h0[2048];
  __shared__ u32 h1[2048];
  __shared__ u64 s_prefix;
  __shared__ int s_remaining;
  __shared__ int s_bin;
  if (threadIdx.x == 0){ s_prefix = 0ull; s_remaining = k; cnt[g] = 0; }
  int consumed = 0;
  for (int round = 0; round < 6; ++round){
    int nb = (round < 5) ? 11 : 9;
    int shift = 64 - consumed - nb;
    int bins = 1 << nb;
    for (int i = threadIdx.x; i < bins; i += 1024) h0[i] = 0u;
    __syncthreads();
    u64 pref = s_prefix;
    int rem = s_remaining;
    for (int i = threadIdx.x; i < n; i += 1024){
      u64 key = kk[i];
      if (consumed == 0 || (key >> (64 - consumed)) == pref)
        atomicAdd(&h0[(u32)((key >> shift) & (u64)(bins-1))], 1u);
    }
    __syncthreads();
    u32* src = h0; u32* dst = h1;
    for (int off = 1; off < bins; off <<= 1){
      for (int i = threadIdx.x; i < bins; i += 1024)
        dst[i] = src[i] + ((i + off < bins) ? src[i + off] : 0u);
      __syncthreads();
      u32* tmp = src; src = dst; dst = tmp;
    }
    for (int i = threadIdx.x; i < bins; i += 1024){
      int Sb  = (int)src[i];
      int Sb1 = (i + 1 < bins) ? (int)src[i+1] : 0;
      if (Sb >= rem && (i == bins-1 || Sb1 < rem)){
        s_bin = i;
        s_remaining = rem - Sb1;
      }
    }
    __syncthreads();
    if (threadIdx.x == 0) s_prefix = (s_prefix << nb) | (u64)s_bin;
    consumed += nb;
    __syncthreads();
  }
  if (threadIdx.x == 0) Tout[g] = s_prefix;
}

// ---- wave-aggregated select ----
__global__ void k_select(const u64* keys, const u64* T, int* mapping,
                         int* perm, int* cnt, int n, int k, int ntot){
  int gi = blockIdx.x*256 + threadIdx.x;
  int lane = threadIdx.x & 63;
  if (gi - lane >= ntot) return;
  int g = gi / n;
  bool sel = keys[gi] >= T[g];
  u64 ball = __ballot(sel);
  u64 lt = (1ull << lane) - 1ull;
  int g0 = __shfl(g, 0);
  u64 sameg = __ballot(g == g0);
  int id = -1;
  if (g == g0){
    u64 mA = ball & sameg;
    int baseA = 0;
    if (lane == 0 && mA) baseA = atomicAdd(&cnt[g0], __popcll(mA));
    baseA = __shfl(baseA, 0);
    if (sel) id = baseA + __popcll(mA & lt);
  } else {
    u64 blanes = ~sameg;
    int firstB = (int)(__ffsll((long long)blanes) - 1);
    u64 mB = ball & blanes;
    int baseB = 0;
    if (lane == firstB && mB) baseB = atomicAdd(&cnt[g], __popcll(mB));
    baseB = __shfl(baseB, firstB);
    if (sel) id = baseB + __popcll(mB & lt);
  }
  mapping[gi] = id;
  if (id >= 0) perm[g*k + id] = gi - g*n;
}

__global__ void k_poolcopy(const float* h, const float* score, const int* perm,
                           float* outA, int n, int k, int D, int mtot){
  int m = blockIdx.x*4 + (threadIdx.x>>6);
  if (m >= mtot) return;
  int lane = threadIdx.x & 63;
  int g = m / k;
  int gi = g*n + perm[m];
  float sc = score[gi];
  const float* row = h + (long)gi*D;
  float* orow = outA + (long)m*D;
  for (int c = lane; c < D; c += 64) orow[c] = row[c]*sc;
}

// ---- tail: partial max + fused finish ----
__global__ void k_maxpart(const float* h, float* part){
  int g = blockIdx.y, b = blockIdx.x, c = threadIdx.x;
  int r0 = b*240;
  const float* base = h + ((long)g*KP3 + r0)*256;
  float m = -3.4e38f;
  for (int r = 0; r < 240; ++r) m = fmaxf(m, base[(long)r*256 + c]);
  part[(g*15 + b)*256 + c] = m;
}

__global__ void k_final(const float* part, const float* lw, const float* lb,
                        const float* l2w, const float* l2b, float* dout){
  __shared__ float sx[256];
  __shared__ float sp[256];
  int c = threadIdx.x;
  float acc4 = 0.0f;
  for (int g = 0; g < NGRAPH; ++g){
    float m = -3.4e38f;
    for (int b = 0; b < 15; ++b) m = fmaxf(m, part[(g*15 + b)*256 + c]);
    acc4 += m;
  }
  float x1 = 0.25f*acc4;
  sx[c] = x1;
  __syncthreads();
  float acc = lb[c];
  for (int j = 0; j < 256; ++j) acc += sx[j]*lw[j*256 + c];
  acc = fmaxf(acc, 0.0f);
  sp[c] = acc*l2w[c];
  __syncthreads();
  for (int off = 128; off > 0; off >>= 1){
    if (c < off) sp[c] += sp[c+off];
    __syncthreads();
  }
  if (c == 0) dout[0] = sp[0] + l2b[0];
  dout[1+c] = sx[c];
}

extern "C" void kernel_launch(void* const* d_in, const int* in_sizes, int n_in,
                              void* d_out, int out_size, void* d_ws, size_t ws_size,
                              hipStream_t stream){
  const float* x  = (const float*)d_in[0];
  const int*   ei = (const int*)d_in[1];
  const float *W1 = (const float*)d_in[2],  *b1 = (const float*)d_in[3];
  const float *W2 = (const float*)d_in[4],  *b2 = (const float*)d_in[5];
  const float *W3 = (const float*)d_in[6],  *b3 = (const float*)d_in[7];
  const float *W4 = (const float*)d_in[8],  *b4 = (const float*)d_in[9];
  const float *g1 = (const float*)d_in[10], *be1 = (const float*)d_in[11];
  const float *g2 = (const float*)d_in[12], *be2 = (const float*)d_in[13];
  const float *g3 = (const float*)d_in[14], *be3 = (const float*)d_in[15];
  const float *p1r = (const float*)d_in[16], *p1b = (const float*)d_in[17], *p1o = (const float*)d_in[18];
  const float *p2r = (const float*)d_in[19], *p2b = (const float*)d_in[20], *p2o = (const float*)d_in[21];
  const float *p3r = (const float*)d_in[22], *p3b = (const float*)d_in[23], *p3o = (const float*)d_in[24];
  const float *lw = (const float*)d_in[25], *lb = (const float*)d_in[26];
  const float *l2w = (const float*)d_in[27], *l2b = (const float*)d_in[28];
  float* dout = (float*)d_out;

  bool ok = (n_in == 29) && (out_size == 257)
         && (in_sizes[0] == NGRAPH*N0*512) && (in_sizes[1] == NGRAPH*2*EDG);
  if (!ok){
    k_probe<<<2,256,0,stream>>>(dout, out_size, 7777777.0f);
    return;
  }

  char* wbase = (char*)d_ws;
  size_t woff = 0;
  auto alloc = [&](size_t bytes) -> void* {
    void* p = wbase + woff;
    woff = (woff + bytes + 255) & ~(size_t)255;
    return p;
  };
  size_t NE = (size_t)NGRAPH*N0;
  size_t RSZ = NE*512*4;
  float* R0 = (float*)alloc(RSZ);
  float* R1 = (float*)alloc(RSZ);
  u16* Wt1h = (u16*)alloc((size_t)512*512*2); u16* Wt1l = (u16*)alloc((size_t)512*512*2);
  u16* Wt2h = (u16*)alloc((size_t)512*512*2); u16* Wt2l = (u16*)alloc((size_t)512*512*2);
  u16* Wt3h = (u16*)alloc((size_t)256*512*2); u16* Wt3l = (u16*)alloc((size_t)256*512*2);
  u16* Wt4h = (u16*)alloc((size_t)256*256*2); u16* Wt4l = (u16*)alloc((size_t)256*256*2);
  int*   esrc  = (int*)alloc((size_t)NGRAPH*EDG*4);
  int*   edst  = (int*)alloc((size_t)NGRAPH*EDG*4);
  int*   csrsA = (int*)  alloc((size_t)NGRAPH*EDG*4);
  float* csrnA = (float*)alloc((size_t)NGRAPH*EDG*4);
  int*   csrsB = (int*)  alloc((size_t)NGRAPH*EDG*4);
  float* csrnB = (float*)alloc((size_t)NGRAPH*EDG*4);
  int*   degA  = (int*)  alloc(NE*4);
  int*   degB  = (int*)  alloc(NE*4);
  int*   offsA = (int*)  alloc((NE+1)*4);
  int*   offsB = (int*)  alloc((NE+1)*4);
  float* dinv  = (float*)alloc(NE*4);
  int*   cursor= (int*)  alloc(NE*4);
  int*   bsum  = (int*)  alloc(128*4);
  float* rbuf  = (float*)alloc(NE*4);
  float* tbuf  = (float*)alloc(NE*4);
  float* sbuf  = (float*)alloc(NE*4);
  u64*   keys  = (u64*)  alloc(NE*8);
  u64*   Tsel  = (u64*)  alloc(NGRAPH*8);
  int*   cnt   = (int*)  alloc(NGRAPH*4);
  int*   mapping = (int*)alloc(NE*4);
  int*   perm  = (int*)  alloc((size_t)NGRAPH*KP1*4);
  float* bnpart= (float*)alloc((size_t)NGRAPH*79*2*512*4);
  float* bnmean= (float*)alloc((size_t)NGRAPH*512*4);
  float* bnrstd= (float*)alloc((size_t)NGRAPH*512*4);
  float* maxpart=(float*)alloc((size_t)NGRAPH*15*256*4);

  if (woff > ws_size){
    k_probe<<<2,256,0,stream>>>(dout, out_size, 8000000.0f + (float)(ws_size >> 20));
    return;
  }

  auto cdiv = [](long a, long b) -> int { return (int)((a + b - 1)/b); };
  long etot = (long)NGRAPH*EDG;

  {
    dim3 g1d(512/32, 512/32);
    k_castw2<<<g1d,256,0,stream>>>(W1, Wt1h, Wt1l, 512, 512);
    k_castw2<<<g1d,256,0,stream>>>(W2, Wt2h, Wt2l, 512, 512);
    dim3 g3d(512/32, 256/32);
    k_castw2<<<g3d,256,0,stream>>>(W3, Wt3h, Wt3l, 512, 256);
    dim3 g4d(256/32, 256/32);
    k_castw2<<<g4d,256,0,stream>>>(W4, Wt4h, Wt4l, 256, 256);
  }
  k_edges_init<<<cdiv(etot,256),256,0,stream>>>(ei, esrc, edst);

  struct SP { int n, din, dout_, knext; const u16 *Wh,*Wl; const float *b,*gam,*bet,*wrel,*brel,*wroot; };
  SP sp[4] = {
    {N0,  512, 512, KP1, Wt1h,Wt1l, b1,g1,be1,p1r,p1b,p1o},
    {KP1, 512, 512, KP2, Wt2h,Wt2l, b2,g2,be2,p2r,p2b,p2o},
    {KP2, 512, 256, KP3, Wt3h,Wt3l, b3,g3,be3,p3r,p3b,p3o},
    {KP3, 256, 256, 0,   Wt4h,Wt4l, b4,0,0,0,0,0},
  };

  float* bufA = R0;
  float* bufB = R1;

  int *deg_c = degA, *offs_c = offsA, *csrs_c = csrsA;
  float *csrn_c = csrnA;
  int *deg_x = degB, *offs_x = offsB, *csrs_x = csrsB;
  float *csrn_x = csrnB;

  for (int s = 0; s < 4; ++s){
    SP& P = sp[s];
    int ntot = NGRAPH*P.n;
    int D = P.dout_;
    const float* Ain = (s == 0) ? x : bufA;
    float* H = bufB;
    float* C = bufA;
    int nb = cdiv(ntot, 1024);

    if (s == 0){
      k_zero_i32<<<cdiv(ntot,256),256,0,stream>>>(deg_c, ntot);
      k_deg<<<cdiv(etot,256),256,0,stream>>>(esrc, edst, deg_c, P.n);
      k_scan1<<<nb,1024,0,stream>>>(deg_c, offs_c, bsum, dinv, ntot);
      k_scan2<<<1,128,0,stream>>>(bsum, offs_c, nb, ntot);
      k_scan3<<<nb,1024,0,stream>>>(offs_c, bsum, cursor, ntot);
      k_csrfill<<<cdiv(etot,256),256,0,stream>>>(esrc, edst, dinv, cursor, csrs_c, csrn_c, P.n);
    } else {
      int n_old = sp[s-1].n;
      k_filterdeg<<<cdiv(ntot,256),256,0,stream>>>(perm, mapping, offs_c, deg_c, csrs_c,
                                                   deg_x, n_old, P.n, ntot);
      k_scan1<<<nb,1024,0,stream>>>(deg_x, offs_x, bsum, dinv, ntot);
      k_scan2<<<1,128,0,stream>>>(bsum, offs_x, nb, ntot);
      k_scan3<<<nb,1024,0,stream>>>(offs_x, bsum, cursor, ntot);
      k_filterfill<<<cdiv(ntot,256),256,0,stream>>>(perm, mapping, offs_c, deg_c, csrs_c,
                                                    offs_x, dinv, csrs_x, csrn_x, n_old, P.n, ntot);
      int* ti; float* tf;
      ti = deg_c;  deg_c  = deg_x;  deg_x  = ti;
      ti = offs_c; offs_c = offs_x; offs_x = ti;
      ti = csrs_c; csrs_c = csrs_x; csrs_x = ti;
      tf = csrn_c; csrn_c = csrn_x; csrn_x = tf;
    }

    {
      dim3 gg(D/128, cdiv(ntot,128));
      k_gemm3<<<gg,256,0,stream>>>(Ain, P.Wh, P.Wl, H, P.din, D);
    }
    if (D == 512)
      hipLaunchKernelGGL(HIP_KERNEL_NAME(k_agg<512>), dim3(ntot/4), dim3(256), 0, stream,
                         H, offs_c, deg_c, csrs_c, csrn_c, P.b, C, ntot);
    else
      hipLaunchKernelGGL(HIP_KERNEL_NAME(k_agg<256>), dim3(ntot/4), dim3(256), 0, stream,
                         H, offs_c, deg_c, csrs_c, csrn_c, P.b, C, ntot);
    if (s < 3){
      int NB = cdiv(P.n, 256);
      if (D == 512)
        hipLaunchKernelGGL(HIP_KERNEL_NAME(k_bnpart<512>), dim3(NB,NGRAPH), dim3(256), 0, stream,
                           C, bnpart, P.n, NB);
      else
        hipLaunchKernelGGL(HIP_KERNEL_NAME(k_bnpart<256>), dim3(NB,NGRAPH), dim3(256), 0, stream,
                           C, bnpart, P.n, NB);
      k_bnfin<<<cdiv((long)NGRAPH*D,256),256,0,stream>>>(bnpart, bnmean, bnrstd, P.n, D, NB);
      if (D == 512)
        hipLaunchKernelGGL(HIP_KERNEL_NAME(k_bnrelu_dots<512>), dim3(ntot/4), dim3(256), 0, stream,
                           C, bnmean, bnrstd, P.gam, P.bet, P.wrel, P.wroot, rbuf, tbuf, P.n, ntot);
      else
        hipLaunchKernelGGL(HIP_KERNEL_NAME(k_bnrelu_dots<256>), dim3(ntot/4), dim3(256), 0, stream,
                           C, bnmean, bnrstd, P.gam, P.bet, P.wrel, P.wroot, rbuf, tbuf, P.n, ntot);
      k_score<<<cdiv(ntot,256),256,0,stream>>>(rbuf, tbuf, offs_c, deg_c, csrs_c, P.brel,
                                               sbuf, keys, P.n, ntot);
      k_radix<<<NGRAPH,1024,0,stream>>>(keys, Tsel, cnt, P.n, P.knext);
      k_select<<<cdiv(ntot,256),256,0,stream>>>(keys, Tsel, mapping, perm, cnt, P.n, P.knext, ntot);
      int mtot = NGRAPH*P.knext;
      k_poolcopy<<<mtot/4,256,0,stream>>>(C, sbuf, perm, bufB, P.n, P.knext, D, mtot);
      float* tmp = bufA; bufA = bufB; bufB = tmp;
    } else {
      k_maxpart<<<dim3(15,NGRAPH),256,0,stream>>>(C, maxpart);
      k_final<<<1,256,0,stream>>>(maxpart, lw, lb, l2w, l2b, dout);
    }
  }
}